// Round 6
// baseline (328.646 us; speedup 1.0000x reference)
//
#include <hip/hip_runtime.h>
#include <hip/hip_bf16.h>

typedef __bf16 bf16_t;
typedef __bf16 bf16x4 __attribute__((ext_vector_type(4)));
typedef __bf16 bf16x8 __attribute__((ext_vector_type(8)));
typedef float f32x4 __attribute__((ext_vector_type(4)));
typedef unsigned int u32;

#define B_ 4
#define N_ 2048
#define C_ 1024
#define H_ 16
#define D_ 64

#define MFMA32(a, b, c) __builtin_amdgcn_mfma_f32_16x16x32_bf16((a), (b), (c), 0, 0, 0)

#if __has_builtin(__builtin_amdgcn_exp2f)
#define EXP2F(x) __builtin_amdgcn_exp2f(x)
#else
#define EXP2F(x) __expf((x) * 0.6931471805599453f)
#endif

// 0.125 (=1/sqrt(D)) * log2(e): folded into Q at projection time
#define QSCALE 0.18033688011112042f

// async global->LDS, 16B per lane; LDS dst is wave-uniform base + lane*16
__device__ __forceinline__ void async16(const bf16_t* g, bf16_t* l) {
    __builtin_amdgcn_global_load_lds(
        (const u32 __attribute__((address_space(1)))*)g,
        (u32 __attribute__((address_space(3)))*)l, 16, 0, 0);
}

// ---------------------------------------------------------------------------
// x: f32 -> bf16 elementwise, 8 elems/thread
// ---------------------------------------------------------------------------
__global__ __launch_bounds__(256)
void xconv_kernel(const float* __restrict__ x, bf16_t* __restrict__ xb)
{
    const size_t i = ((size_t)blockIdx.x * 256 + threadIdx.x) * 8;
    float4 a = *(const float4*)(x + i);
    float4 b = *(const float4*)(x + i + 4);
    bf16x8 o;
    o[0] = (bf16_t)a.x; o[1] = (bf16_t)a.y; o[2] = (bf16_t)a.z; o[3] = (bf16_t)a.w;
    o[4] = (bf16_t)b.x; o[5] = (bf16_t)b.y; o[6] = (bf16_t)b.z; o[7] = (bf16_t)b.w;
    *(bf16x8*)(xb + i) = o;
}

// ---------------------------------------------------------------------------
// W[K][N] f32 -> Wt[N][K] bf16 (64x64 LDS tile transpose; z picks weight)
// ---------------------------------------------------------------------------
__global__ __launch_bounds__(256)
void wtrans_kernel(const float* __restrict__ W0, const float* __restrict__ W1,
                   const float* __restrict__ W2, const float* __restrict__ W3,
                   bf16_t* __restrict__ T0, bf16_t* __restrict__ T1,
                   bf16_t* __restrict__ T2, bf16_t* __restrict__ T3)
{
    const float* W; bf16_t* T;
    switch (blockIdx.z) {
        case 0:  W = W0; T = T0; break;
        case 1:  W = W1; T = T1; break;
        case 2:  W = W2; T = T2; break;
        default: W = W3; T = T3; break;
    }
    __shared__ bf16_t tile[64 * 72];
    const int tid = threadIdx.x;
    const int r0 = blockIdx.y * 64;          // k block
    const int c0 = blockIdx.x * 64;          // n block

    const int rr = tid >> 4;
    const int cc = (tid & 15) * 4;
    #pragma unroll
    for (int i = 0; i < 4; ++i) {
        const int row = rr + i * 16;
        float4 v = *(const float4*)(W + (size_t)(r0 + row) * C_ + c0 + cc);
        tile[(cc + 0) * 72 + row] = (bf16_t)v.x;
        tile[(cc + 1) * 72 + row] = (bf16_t)v.y;
        tile[(cc + 2) * 72 + row] = (bf16_t)v.z;
        tile[(cc + 3) * 72 + row] = (bf16_t)v.w;
    }
    __syncthreads();
    #pragma unroll
    for (int i = 0; i < 2; ++i) {
        const int ch = i * 256 + tid;
        const int n  = ch >> 3;
        const int k8 = (ch & 7) * 8;
        bf16x8 o = *(const bf16x8*)&tile[n * 72 + k8];
        *(bf16x8*)(T + (size_t)(c0 + n) * C_ + r0 + k8) = o;
    }
}

// ---------------------------------------------------------------------------
// Fused QKV GEMM: A[8192,1024]bf16 @ Wqkv_t[3072,1024]^T + bias.
// 128x128 tile, BK=32 (BK=64 would make LDS row stride 128B -> 16-way frag
// read conflicts with lane-contiguous async staging; keep 32).
// Epilogue routes by which = n0>>10: 0 -> Qb [B,H,N,D] PRE-SCALED by QSCALE,
// 1 -> Kb [B,H,N,D], 2 -> Vtb [B,H,D,N] (packed 8B stores).
// ---------------------------------------------------------------------------
__global__ __launch_bounds__(256)
void gemm_qkv_kernel(const bf16_t* __restrict__ A, const bf16_t* __restrict__ Wt,
                     const float* __restrict__ bq, const float* __restrict__ bk,
                     const float* __restrict__ bv,
                     bf16_t* __restrict__ Qb, bf16_t* __restrict__ Kb,
                     bf16_t* __restrict__ Vtb)
{
    __shared__ bf16_t As[128 * 32];
    __shared__ bf16_t Bs[128 * 32];

    const int tid  = threadIdx.x;
    const int w    = tid >> 6;
    const int lane = tid & 63;
    const int c    = lane & 15;
    const int quad = lane >> 4;
    const int n0   = blockIdx.x * 128;
    const int m0   = blockIdx.y * 128;
    const int wm   = (w & 1) * 64;
    const int wn   = (w >> 1) * 64;

    f32x4 acc[4][4] = {};

    for (int k0 = 0; k0 < C_; k0 += 32) {
        __syncthreads();
        #pragma unroll
        for (int ph = 0; ph < 2; ++ph) {
            const int ch  = ph * 256 + tid;
            const int row = ch >> 2;
            const int k8  = (ch & 3) * 8;
            const int wbase = (ph * 256 + w * 64) * 8;
            async16(A  + (size_t)(m0 + row) * C_ + k0 + k8, &As[wbase]);
            async16(Wt + (size_t)(n0 + row) * C_ + k0 + k8, &Bs[wbase]);
        }
        __syncthreads();

        bf16x8 af[4], bfr[4];
        #pragma unroll
        for (int mf = 0; mf < 4; ++mf)
            af[mf] = *(const bf16x8*)&As[(wm + mf * 16 + c) * 32 + quad * 8];
        #pragma unroll
        for (int nf = 0; nf < 4; ++nf)
            bfr[nf] = *(const bf16x8*)&Bs[(wn + nf * 16 + c) * 32 + quad * 8];

        #pragma unroll
        for (int mf = 0; mf < 4; ++mf)
            #pragma unroll
            for (int nf = 0; nf < 4; ++nf)
                acc[mf][nf] = MFMA32(af[mf], bfr[nf], acc[mf][nf]);
    }

    const int which = n0 >> 10;                 // 0 Q, 1 K, 2 V (tile-uniform)
    const float* bias = (which == 0) ? bq : (which == 1) ? bk : bv;

    #pragma unroll
    for (int nf = 0; nf < 4; ++nf) {
        const int col  = n0 + wn + nf * 16 + c;
        const int ncol = col & 1023;
        const float bsf = bias[ncol];
        const int h = ncol >> 6, d = ncol & 63;
        #pragma unroll
        for (int mf = 0; mf < 4; ++mf) {
            const int rbase = m0 + wm + mf * 16 + quad * 4;
            if (which < 2) {
                bf16_t* out = which ? Kb : Qb;
                const float sc = which ? 1.0f : QSCALE;
                #pragma unroll
                for (int r = 0; r < 4; ++r) {
                    const int row = rbase + r;
                    const int bb = row >> 11, n = row & 2047;
                    out[(((size_t)bb * H_ + h) * N_ + n) * D_ + d] =
                        (bf16_t)((acc[mf][nf][r] + bsf) * sc);
                }
            } else {
                const int bb = rbase >> 11, nb = rbase & 2047;
                bf16x4 o;
                #pragma unroll
                for (int r = 0; r < 4; ++r) o[r] = (bf16_t)(acc[mf][nf][r] + bsf);
                *(bf16x4*)(Vtb + (((size_t)bb * H_ + h) * D_ + d) * N_ + nb) = o;
            }
        }
    }
}

// ---------------------------------------------------------------------------
// Output GEMM: ctx[8192,1024]bf16 @ Wo_t[1024,1024]^T + bo -> f32 [8192,1024]
// ---------------------------------------------------------------------------
__global__ __launch_bounds__(256)
void gemm_out_kernel(const bf16_t* __restrict__ A, const bf16_t* __restrict__ Bt,
                     const float* __restrict__ bias, float* __restrict__ out)
{
    __shared__ bf16_t As[128 * 32];
    __shared__ bf16_t Bs[128 * 32];

    const int tid  = threadIdx.x;
    const int w    = tid >> 6;
    const int lane = tid & 63;
    const int c    = lane & 15;
    const int quad = lane >> 4;
    const int n0   = blockIdx.x * 128;
    const int m0   = blockIdx.y * 128;
    const int wm   = (w & 1) * 64;
    const int wn   = (w >> 1) * 64;

    f32x4 acc[4][4] = {};

    for (int k0 = 0; k0 < C_; k0 += 32) {
        __syncthreads();
        #pragma unroll
        for (int ph = 0; ph < 2; ++ph) {
            const int ch  = ph * 256 + tid;
            const int row = ch >> 2;
            const int k8  = (ch & 3) * 8;
            const int wbase = (ph * 256 + w * 64) * 8;
            async16(A  + (size_t)(m0 + row) * C_ + k0 + k8, &As[wbase]);
            async16(Bt + (size_t)(n0 + row) * C_ + k0 + k8, &Bs[wbase]);
        }
        __syncthreads();

        bf16x8 af[4], bfr[4];
        #pragma unroll
        for (int mf = 0; mf < 4; ++mf)
            af[mf] = *(const bf16x8*)&As[(wm + mf * 16 + c) * 32 + quad * 8];
        #pragma unroll
        for (int nf = 0; nf < 4; ++nf)
            bfr[nf] = *(const bf16x8*)&Bs[(wn + nf * 16 + c) * 32 + quad * 8];

        #pragma unroll
        for (int mf = 0; mf < 4; ++mf)
            #pragma unroll
            for (int nf = 0; nf < 4; ++nf)
                acc[mf][nf] = MFMA32(af[mf], bfr[nf], acc[mf][nf]);
    }

    #pragma unroll
    for (int nf = 0; nf < 4; ++nf) {
        const int col   = n0 + wn + nf * 16 + c;
        const float bsf = bias[col];
        #pragma unroll
        for (int mf = 0; mf < 4; ++mf) {
            const int rbase = m0 + wm + mf * 16 + quad * 4;
            #pragma unroll
            for (int r = 0; r < 4; ++r)
                out[(size_t)(rbase + r) * C_ + col] = acc[mf][nf][r] + bsf;
        }
    }
}

// ---------------------------------------------------------------------------
// Attention, S^T formulation, no-rescale streaming softmax, prescaled Q.
// Q comes in already multiplied by 0.125*log2(e), so p = exp2(s) directly.
// Row-sum l accumulated by an extra ones-row MFMA (every lane ends with the
// full l for its q=c; no cross-lane reduction needed).
// Block = 4 waves, 64 q-rows (wave: 16 q). Key tiles of 64 staged in LDS
// (XOR-swizzled 16B chunks). Grid 2048; head = (bid&7)*8 + ((bid>>3)&7).
// ---------------------------------------------------------------------------
__global__ __launch_bounds__(256, 8)
void attn_kernel(const bf16_t* __restrict__ Q, const bf16_t* __restrict__ K,
                 const bf16_t* __restrict__ Vt, bf16_t* __restrict__ ctx)
{
    __shared__ bf16_t ksh[64 * 64];
    __shared__ bf16_t vsh[64 * 64];

    const int tid  = threadIdx.x;
    const int w    = tid >> 6;
    const int lane = tid & 63;
    const int c    = lane & 15;
    const int quad = lane >> 4;

    const int bid   = blockIdx.x;
    const int slot  = bid >> 3;
    const int bh    = (bid & 7) * 8 + (slot & 7);   // 0..63
    const int qtile = slot >> 3;                    // 0..31
    const int b = bh >> 4, h = bh & 15;
    const size_t base = (size_t)bh * N_ * D_;
    const int qg = qtile * 64 + w * 16;             // this wave's 16 q-rows

    bf16x8 qf[2];
    #pragma unroll
    for (int hh = 0; hh < 2; ++hh)
        qf[hh] = *(const bf16x8*)(Q + base + (size_t)(qg + c) * D_ + hh * 32 + quad * 8);

    bf16x8 ones;
    #pragma unroll
    for (int j = 0; j < 8; ++j) ones[j] = (bf16_t)1.0f;

    f32x4 O[4] = {};
    f32x4 O5 = {};                                  // row-sum accumulator

    for (int kt = 0; kt < N_; kt += 64) {
        __syncthreads();
        #pragma unroll
        for (int ph = 0; ph < 2; ++ph) {
            const int ch = ph * 256 + tid;       // 0..511
            const int rr = ch >> 3;              // key (K) / d (V)
            const int e8 = ch & 7;
            const int sw = (e8 ^ (rr & 7)) * 8;
            bf16x8 kv = *(const bf16x8*)(K  + base + (size_t)(kt + rr) * D_ + e8 * 8);
            *(bf16x8*)&ksh[rr * 64 + sw] = kv;
            bf16x8 vv = *(const bf16x8*)(Vt + base + (size_t)rr * N_ + kt + e8 * 8);
            *(bf16x8*)&vsh[rr * 64 + sw] = vv;
        }
        __syncthreads();

        #pragma unroll
        for (int ss = 0; ss < 2; ++ss) {         // two 32-key sub-steps
            bf16x8 kb[2][2];
            #pragma unroll
            for (int s2 = 0; s2 < 2; ++s2) {
                const int key = (ss * 2 + s2) * 16 + c;
                #pragma unroll
                for (int hh = 0; hh < 2; ++hh)
                    kb[s2][hh] = *(const bf16x8*)&ksh[key * 64 + (((hh * 4 + quad) ^ (c & 7)) * 8)];
            }
            bf16x8 va[4];
            const int k8lo = ss * 4 + (quad >> 1);
            const int half = (quad & 1) * 4;
            #pragma unroll
            for (int df = 0; df < 4; ++df) {
                const int row = (df * 16 + c) * 64;
                bf16x4 lo = *(const bf16x4*)&vsh[row + ((k8lo       ^ (c & 7)) * 8) + half];
                bf16x4 hi = *(const bf16x4*)&vsh[row + (((k8lo + 2) ^ (c & 7)) * 8) + half];
                #pragma unroll
                for (int j = 0; j < 4; ++j) { va[df][j] = lo[j]; va[df][4 + j] = hi[j]; }
            }

            f32x4 s0 = {}, s1 = {};
            s0 = MFMA32(kb[0][0], qf[0], s0);
            s0 = MFMA32(kb[0][1], qf[1], s0);
            s1 = MFMA32(kb[1][0], qf[0], s1);
            s1 = MFMA32(kb[1][1], qf[1], s1);

            bf16x8 pb;
            #pragma unroll
            for (int r = 0; r < 4; ++r) {
                pb[r]     = (bf16_t)EXP2F(s0[r]);
                pb[4 + r] = (bf16_t)EXP2F(s1[r]);
            }

            #pragma unroll
            for (int df = 0; df < 4; ++df)
                O[df] = MFMA32(va[df], pb, O[df]);
            O5 = MFMA32(ones, pb, O5);           // l accumulation
        }
    }

    const float inv_l = 1.0f / O5[0];            // full row-sum for q=c

    const int q = qg + c;
    #pragma unroll
    for (int df = 0; df < 4; ++df) {
        bf16x4 o;
        #pragma unroll
        for (int r = 0; r < 4; ++r) o[r] = (bf16_t)(O[df][r] * inv_l);
        *(bf16x4*)(ctx + ((size_t)b * N_ + q) * C_ + h * 64 + df * 16 + quad * 4) = o;
    }
}

extern "C" void kernel_launch(void* const* d_in, const int* in_sizes, int n_in,
                              void* d_out, int out_size, void* d_ws, size_t ws_size,
                              hipStream_t stream) {
    const float* x  = (const float*)d_in[0];
    const float* Wq = (const float*)d_in[1];
    const float* bq = (const float*)d_in[2];
    const float* Wk = (const float*)d_in[3];
    const float* bk = (const float*)d_in[4];
    const float* Wv = (const float*)d_in[5];
    const float* bv = (const float*)d_in[6];
    const float* Wo = (const float*)d_in[7];
    const float* bo = (const float*)d_in[8];

    bf16_t* ws = (bf16_t*)d_ws;
    const size_t per = (size_t)B_ * N_ * C_;     // 8,388,608 elems
    bf16_t* xb  = ws;                            // reused as ctx after QKV
    bf16_t* ctx = ws;
    bf16_t* Qb  = ws + per;
    bf16_t* Kb  = ws + 2 * per;
    bf16_t* Vtb = ws + 3 * per;
    bf16_t* Wtqkv = ws + 4 * per;                // [3072][1024] concatenated
    bf16_t* Wtq = Wtqkv;
    bf16_t* Wtk = Wtqkv + (size_t)C_ * C_;
    bf16_t* Wtv = Wtqkv + 2 * (size_t)C_ * C_;
    bf16_t* Wto = Wtqkv + 3 * (size_t)C_ * C_;

    dim3 blk(256);

    xconv_kernel<<<dim3(per / 2048), blk, 0, stream>>>(x, xb);
    wtrans_kernel<<<dim3(16, 16, 4), blk, 0, stream>>>(Wq, Wk, Wv, Wo, Wtq, Wtk, Wtv, Wto);

    gemm_qkv_kernel<<<dim3(24, 64), blk, 0, stream>>>(xb, Wtqkv, bq, bk, bv, Qb, Kb, Vtb);

    attn_kernel<<<dim3(2048), blk, 0, stream>>>(Qb, Kb, Vtb, ctx);

    gemm_out_kernel<<<dim3(8, 64), blk, 0, stream>>>(ctx, Wto, bo, (float*)d_out);
}

// Round 7
// 276.195 us; speedup vs baseline: 1.1899x; 1.1899x over previous
//
#include <hip/hip_runtime.h>
#include <hip/hip_bf16.h>

typedef __bf16 bf16_t;
typedef __bf16 bf16x4 __attribute__((ext_vector_type(4)));
typedef __bf16 bf16x8 __attribute__((ext_vector_type(8)));
typedef float f32x4 __attribute__((ext_vector_type(4)));
typedef unsigned int u32;

#define B_ 4
#define N_ 2048
#define C_ 1024
#define H_ 16
#define D_ 64

#define MFMA32(a, b, c) __builtin_amdgcn_mfma_f32_16x16x32_bf16((a), (b), (c), 0, 0, 0)

#if __has_builtin(__builtin_amdgcn_exp2f)
#define EXP2F(x) __builtin_amdgcn_exp2f(x)
#else
#define EXP2F(x) __expf((x) * 0.6931471805599453f)
#endif

// 0.125 (=1/sqrt(D)) * log2(e): folded into Q at projection time
#define QSCALE 0.18033688011112042f

// async global->LDS, 16B per lane; LDS dst is wave-uniform base + lane*16
__device__ __forceinline__ void async16(const bf16_t* g, bf16_t* l) {
    __builtin_amdgcn_global_load_lds(
        (const u32 __attribute__((address_space(1)))*)g,
        (u32 __attribute__((address_space(3)))*)l, 16, 0, 0);
}

// ---------------------------------------------------------------------------
// x: f32 -> bf16 elementwise, 8 elems/thread
// ---------------------------------------------------------------------------
__global__ __launch_bounds__(256)
void xconv_kernel(const float* __restrict__ x, bf16_t* __restrict__ xb)
{
    const size_t i = ((size_t)blockIdx.x * 256 + threadIdx.x) * 8;
    float4 a = *(const float4*)(x + i);
    float4 b = *(const float4*)(x + i + 4);
    bf16x8 o;
    o[0] = (bf16_t)a.x; o[1] = (bf16_t)a.y; o[2] = (bf16_t)a.z; o[3] = (bf16_t)a.w;
    o[4] = (bf16_t)b.x; o[5] = (bf16_t)b.y; o[6] = (bf16_t)b.z; o[7] = (bf16_t)b.w;
    *(bf16x8*)(xb + i) = o;
}

// ---------------------------------------------------------------------------
// W[K][N] f32 -> Wt[N][K] bf16 (64x64 LDS tile transpose; z picks weight)
// ---------------------------------------------------------------------------
__global__ __launch_bounds__(256)
void wtrans_kernel(const float* __restrict__ W0, const float* __restrict__ W1,
                   const float* __restrict__ W2, const float* __restrict__ W3,
                   bf16_t* __restrict__ T0, bf16_t* __restrict__ T1,
                   bf16_t* __restrict__ T2, bf16_t* __restrict__ T3)
{
    const float* W; bf16_t* T;
    switch (blockIdx.z) {
        case 0:  W = W0; T = T0; break;
        case 1:  W = W1; T = T1; break;
        case 2:  W = W2; T = T2; break;
        default: W = W3; T = T3; break;
    }
    __shared__ bf16_t tile[64 * 72];
    const int tid = threadIdx.x;
    const int r0 = blockIdx.y * 64;          // k block
    const int c0 = blockIdx.x * 64;          // n block

    const int rr = tid >> 4;
    const int cc = (tid & 15) * 4;
    #pragma unroll
    for (int i = 0; i < 4; ++i) {
        const int row = rr + i * 16;
        float4 v = *(const float4*)(W + (size_t)(r0 + row) * C_ + c0 + cc);
        tile[(cc + 0) * 72 + row] = (bf16_t)v.x;
        tile[(cc + 1) * 72 + row] = (bf16_t)v.y;
        tile[(cc + 2) * 72 + row] = (bf16_t)v.z;
        tile[(cc + 3) * 72 + row] = (bf16_t)v.w;
    }
    __syncthreads();
    #pragma unroll
    for (int i = 0; i < 2; ++i) {
        const int ch = i * 256 + tid;
        const int n  = ch >> 3;
        const int k8 = (ch & 7) * 8;
        bf16x8 o = *(const bf16x8*)&tile[n * 72 + k8];
        *(bf16x8*)(T + (size_t)(c0 + n) * C_ + r0 + k8) = o;
    }
}

// ---------------------------------------------------------------------------
// Fused QKV GEMM: A[8192,1024]bf16 @ Wqkv_t[3072,1024]^T + bias.
// 128x128 tile, BK=32, m97-style global_load_lds staging.
// Epilogue routes by which = n0>>10: 0 -> Qb [B,H,N,D] PRE-SCALED by QSCALE,
// 1 -> Kb [B,H,N,D], 2 -> Vtb [B,H,D,N] (packed 8B stores).
// ---------------------------------------------------------------------------
__global__ __launch_bounds__(256)
void gemm_qkv_kernel(const bf16_t* __restrict__ A, const bf16_t* __restrict__ Wt,
                     const float* __restrict__ bq, const float* __restrict__ bk,
                     const float* __restrict__ bv,
                     bf16_t* __restrict__ Qb, bf16_t* __restrict__ Kb,
                     bf16_t* __restrict__ Vtb)
{
    __shared__ bf16_t As[128 * 32];
    __shared__ bf16_t Bs[128 * 32];

    const int tid  = threadIdx.x;
    const int w    = tid >> 6;
    const int lane = tid & 63;
    const int c    = lane & 15;
    const int quad = lane >> 4;
    const int n0   = blockIdx.x * 128;
    const int m0   = blockIdx.y * 128;
    const int wm   = (w & 1) * 64;
    const int wn   = (w >> 1) * 64;

    f32x4 acc[4][4] = {};

    for (int k0 = 0; k0 < C_; k0 += 32) {
        __syncthreads();
        #pragma unroll
        for (int ph = 0; ph < 2; ++ph) {
            const int ch  = ph * 256 + tid;
            const int row = ch >> 2;
            const int k8  = (ch & 3) * 8;
            const int wbase = (ph * 256 + w * 64) * 8;
            async16(A  + (size_t)(m0 + row) * C_ + k0 + k8, &As[wbase]);
            async16(Wt + (size_t)(n0 + row) * C_ + k0 + k8, &Bs[wbase]);
        }
        __syncthreads();

        bf16x8 af[4], bfr[4];
        #pragma unroll
        for (int mf = 0; mf < 4; ++mf)
            af[mf] = *(const bf16x8*)&As[(wm + mf * 16 + c) * 32 + quad * 8];
        #pragma unroll
        for (int nf = 0; nf < 4; ++nf)
            bfr[nf] = *(const bf16x8*)&Bs[(wn + nf * 16 + c) * 32 + quad * 8];

        #pragma unroll
        for (int mf = 0; mf < 4; ++mf)
            #pragma unroll
            for (int nf = 0; nf < 4; ++nf)
                acc[mf][nf] = MFMA32(af[mf], bfr[nf], acc[mf][nf]);
    }

    const int which = n0 >> 10;                 // 0 Q, 1 K, 2 V (tile-uniform)
    const float* bias = (which == 0) ? bq : (which == 1) ? bk : bv;

    #pragma unroll
    for (int nf = 0; nf < 4; ++nf) {
        const int col  = n0 + wn + nf * 16 + c;
        const int ncol = col & 1023;
        const float bsf = bias[ncol];
        const int h = ncol >> 6, d = ncol & 63;
        #pragma unroll
        for (int mf = 0; mf < 4; ++mf) {
            const int rbase = m0 + wm + mf * 16 + quad * 4;
            if (which < 2) {
                bf16_t* out = which ? Kb : Qb;
                const float sc = which ? 1.0f : QSCALE;
                #pragma unroll
                for (int r = 0; r < 4; ++r) {
                    const int row = rbase + r;
                    const int bb = row >> 11, n = row & 2047;
                    out[(((size_t)bb * H_ + h) * N_ + n) * D_ + d] =
                        (bf16_t)((acc[mf][nf][r] + bsf) * sc);
                }
            } else {
                const int bb = rbase >> 11, nb = rbase & 2047;
                bf16x4 o;
                #pragma unroll
                for (int r = 0; r < 4; ++r) o[r] = (bf16_t)(acc[mf][nf][r] + bsf);
                *(bf16x4*)(Vtb + (((size_t)bb * H_ + h) * D_ + d) * N_ + nb) = o;
            }
        }
    }
}

// ---------------------------------------------------------------------------
// Output GEMM: ctx[8192,1024]bf16 @ Wo_t[1024,1024]^T + bo -> f32 [8192,1024]
// ---------------------------------------------------------------------------
__global__ __launch_bounds__(256)
void gemm_out_kernel(const bf16_t* __restrict__ A, const bf16_t* __restrict__ Bt,
                     const float* __restrict__ bias, float* __restrict__ out)
{
    __shared__ bf16_t As[128 * 32];
    __shared__ bf16_t Bs[128 * 32];

    const int tid  = threadIdx.x;
    const int w    = tid >> 6;
    const int lane = tid & 63;
    const int c    = lane & 15;
    const int quad = lane >> 4;
    const int n0   = blockIdx.x * 128;
    const int m0   = blockIdx.y * 128;
    const int wm   = (w & 1) * 64;
    const int wn   = (w >> 1) * 64;

    f32x4 acc[4][4] = {};

    for (int k0 = 0; k0 < C_; k0 += 32) {
        __syncthreads();
        #pragma unroll
        for (int ph = 0; ph < 2; ++ph) {
            const int ch  = ph * 256 + tid;
            const int row = ch >> 2;
            const int k8  = (ch & 3) * 8;
            const int wbase = (ph * 256 + w * 64) * 8;
            async16(A  + (size_t)(m0 + row) * C_ + k0 + k8, &As[wbase]);
            async16(Bt + (size_t)(n0 + row) * C_ + k0 + k8, &Bs[wbase]);
        }
        __syncthreads();

        bf16x8 af[4], bfr[4];
        #pragma unroll
        for (int mf = 0; mf < 4; ++mf)
            af[mf] = *(const bf16x8*)&As[(wm + mf * 16 + c) * 32 + quad * 8];
        #pragma unroll
        for (int nf = 0; nf < 4; ++nf)
            bfr[nf] = *(const bf16x8*)&Bs[(wn + nf * 16 + c) * 32 + quad * 8];

        #pragma unroll
        for (int mf = 0; mf < 4; ++mf)
            #pragma unroll
            for (int nf = 0; nf < 4; ++nf)
                acc[mf][nf] = MFMA32(af[mf], bfr[nf], acc[mf][nf]);
    }

    #pragma unroll
    for (int nf = 0; nf < 4; ++nf) {
        const int col   = n0 + wn + nf * 16 + c;
        const float bsf = bias[col];
        #pragma unroll
        for (int mf = 0; mf < 4; ++mf) {
            const int rbase = m0 + wm + mf * 16 + quad * 4;
            #pragma unroll
            for (int r = 0; r < 4; ++r)
                out[(size_t)(rbase + r) * C_ + col] = acc[mf][nf][r] + bsf;
        }
    }
}

// ---------------------------------------------------------------------------
// Attention, S^T formulation, no-rescale streaming softmax, prescaled Q.
// Block = 4 waves, 128 q (wave: 32 q = 2 groups of 16 sharing K/V frags).
// Key tiles of 64 staged in LDS (XOR-swizzled 16B chunks).
// l via ones-row MFMA per group. launch_bounds(256,4): no spills (round-6's
// (256,8) forced ~47 MB of scratch traffic, VGPR squeezed to 32).
// Grid 1024; bh = (bid&7)*8 + ((bid>>3)&7), qtile = bid>>6 (XCD L2 reuse).
// ---------------------------------------------------------------------------
__global__ __launch_bounds__(256, 4)
void attn_kernel(const bf16_t* __restrict__ Q, const bf16_t* __restrict__ K,
                 const bf16_t* __restrict__ Vt, bf16_t* __restrict__ ctx)
{
    __shared__ bf16_t ksh[64 * 64];
    __shared__ bf16_t vsh[64 * 64];

    const int tid  = threadIdx.x;
    const int w    = tid >> 6;
    const int lane = tid & 63;
    const int c    = lane & 15;
    const int quad = lane >> 4;

    const int bid   = blockIdx.x;
    const int bh    = (bid & 7) * 8 + ((bid >> 3) & 7);   // 0..63
    const int qtile = bid >> 6;                           // 0..15
    const int b = bh >> 4, h = bh & 15;
    const size_t base = (size_t)bh * N_ * D_;
    const int qb = qtile * 128 + w * 32;                  // wave's 32 q-rows

    bf16x8 qf[2][2];
    #pragma unroll
    for (int g = 0; g < 2; ++g)
        #pragma unroll
        for (int hh = 0; hh < 2; ++hh)
            qf[g][hh] = *(const bf16x8*)(Q + base + (size_t)(qb + g * 16 + c) * D_ + hh * 32 + quad * 8);

    bf16x8 ones;
    #pragma unroll
    for (int j = 0; j < 8; ++j) ones[j] = (bf16_t)1.0f;

    f32x4 O[2][4] = {};
    f32x4 O5[2] = {};                               // row-sum accumulators

    for (int kt = 0; kt < N_; kt += 64) {
        __syncthreads();
        #pragma unroll
        for (int ph = 0; ph < 2; ++ph) {
            const int ch = ph * 256 + tid;       // 0..511
            const int rr = ch >> 3;              // key (K) / d (V)
            const int e8 = ch & 7;
            const int sw = (e8 ^ (rr & 7)) * 8;
            bf16x8 kv = *(const bf16x8*)(K  + base + (size_t)(kt + rr) * D_ + e8 * 8);
            *(bf16x8*)&ksh[rr * 64 + sw] = kv;
            bf16x8 vv = *(const bf16x8*)(Vt + base + (size_t)rr * N_ + kt + e8 * 8);
            *(bf16x8*)&vsh[rr * 64 + sw] = vv;
        }
        __syncthreads();

        #pragma unroll
        for (int ss = 0; ss < 2; ++ss) {         // two 32-key sub-steps
            bf16x8 kb[2][2];
            #pragma unroll
            for (int s2 = 0; s2 < 2; ++s2) {
                const int key = (ss * 2 + s2) * 16 + c;
                #pragma unroll
                for (int hh = 0; hh < 2; ++hh)
                    kb[s2][hh] = *(const bf16x8*)&ksh[key * 64 + (((hh * 4 + quad) ^ (c & 7)) * 8)];
            }
            bf16x8 va[4];
            const int k8lo = ss * 4 + (quad >> 1);
            const int half = (quad & 1) * 4;
            #pragma unroll
            for (int df = 0; df < 4; ++df) {
                const int row = (df * 16 + c) * 64;
                bf16x4 lo = *(const bf16x4*)&vsh[row + ((k8lo       ^ (c & 7)) * 8) + half];
                bf16x4 hi = *(const bf16x4*)&vsh[row + (((k8lo + 2) ^ (c & 7)) * 8) + half];
                #pragma unroll
                for (int j = 0; j < 4; ++j) { va[df][j] = lo[j]; va[df][4 + j] = hi[j]; }
            }

            #pragma unroll
            for (int g = 0; g < 2; ++g) {
                f32x4 s0 = {}, s1 = {};
                s0 = MFMA32(kb[0][0], qf[g][0], s0);
                s0 = MFMA32(kb[0][1], qf[g][1], s0);
                s1 = MFMA32(kb[1][0], qf[g][0], s1);
                s1 = MFMA32(kb[1][1], qf[g][1], s1);

                bf16x8 pb;
                #pragma unroll
                for (int r = 0; r < 4; ++r) {
                    pb[r]     = (bf16_t)EXP2F(s0[r]);
                    pb[4 + r] = (bf16_t)EXP2F(s1[r]);
                }

                #pragma unroll
                for (int df = 0; df < 4; ++df)
                    O[g][df] = MFMA32(va[df], pb, O[g][df]);
                O5[g] = MFMA32(ones, pb, O5[g]);   // l accumulation
            }
        }
    }

    #pragma unroll
    for (int g = 0; g < 2; ++g) {
        const float inv_l = 1.0f / O5[g][0];       // full row-sum for q
        const int q = qb + g * 16 + c;
        #pragma unroll
        for (int df = 0; df < 4; ++df) {
            bf16x4 o;
            #pragma unroll
            for (int r = 0; r < 4; ++r) o[r] = (bf16_t)(O[g][df][r] * inv_l);
            *(bf16x4*)(ctx + ((size_t)b * N_ + q) * C_ + h * 64 + df * 16 + quad * 4) = o;
        }
    }
}

extern "C" void kernel_launch(void* const* d_in, const int* in_sizes, int n_in,
                              void* d_out, int out_size, void* d_ws, size_t ws_size,
                              hipStream_t stream) {
    const float* x  = (const float*)d_in[0];
    const float* Wq = (const float*)d_in[1];
    const float* bq = (const float*)d_in[2];
    const float* Wk = (const float*)d_in[3];
    const float* bk = (const float*)d_in[4];
    const float* Wv = (const float*)d_in[5];
    const float* bv = (const float*)d_in[6];
    const float* Wo = (const float*)d_in[7];
    const float* bo = (const float*)d_in[8];

    bf16_t* ws = (bf16_t*)d_ws;
    const size_t per = (size_t)B_ * N_ * C_;     // 8,388,608 elems
    bf16_t* xb  = ws;                            // reused as ctx after QKV
    bf16_t* ctx = ws;
    bf16_t* Qb  = ws + per;
    bf16_t* Kb  = ws + 2 * per;
    bf16_t* Vtb = ws + 3 * per;
    bf16_t* Wtqkv = ws + 4 * per;                // [3072][1024] concatenated
    bf16_t* Wtq = Wtqkv;
    bf16_t* Wtk = Wtqkv + (size_t)C_ * C_;
    bf16_t* Wtv = Wtqkv + 2 * (size_t)C_ * C_;
    bf16_t* Wto = Wtqkv + 3 * (size_t)C_ * C_;

    dim3 blk(256);

    xconv_kernel<<<dim3(per / 2048), blk, 0, stream>>>(x, xb);
    wtrans_kernel<<<dim3(16, 16, 4), blk, 0, stream>>>(Wq, Wk, Wv, Wo, Wtq, Wtk, Wtv, Wto);

    gemm_qkv_kernel<<<dim3(24, 64), blk, 0, stream>>>(xb, Wtqkv, bq, bk, bv, Qb, Kb, Vtb);

    attn_kernel<<<dim3(1024), blk, 0, stream>>>(Qb, Kb, Vtb, ctx);

    gemm_out_kernel<<<dim3(8, 64), blk, 0, stream>>>(ctx, Wto, bo, (float*)d_out);
}

// Round 8
// 267.649 us; speedup vs baseline: 1.2279x; 1.0319x over previous
//
#include <hip/hip_runtime.h>
#include <hip/hip_bf16.h>

typedef __bf16 bf16_t;
typedef __bf16 bf16x4 __attribute__((ext_vector_type(4)));
typedef __bf16 bf16x8 __attribute__((ext_vector_type(8)));
typedef float f32x4 __attribute__((ext_vector_type(4)));
typedef unsigned int u32;

#define B_ 4
#define N_ 2048
#define C_ 1024
#define H_ 16
#define D_ 64

#define MFMA32(a, b, c) __builtin_amdgcn_mfma_f32_16x16x32_bf16((a), (b), (c), 0, 0, 0)

#if __has_builtin(__builtin_amdgcn_exp2f)
#define EXP2F(x) __builtin_amdgcn_exp2f(x)
#else
#define EXP2F(x) __expf((x) * 0.6931471805599453f)
#endif

// 0.125 (=1/sqrt(D)) * log2(e): folded into Q at projection time
#define QSCALE 0.18033688011112042f

// async global->LDS, 16B per lane; LDS dst is wave-uniform base + lane*16
__device__ __forceinline__ void async16(const bf16_t* g, bf16_t* l) {
    __builtin_amdgcn_global_load_lds(
        (const u32 __attribute__((address_space(1)))*)g,
        (u32 __attribute__((address_space(3)))*)l, 16, 0, 0);
}

// ---------------------------------------------------------------------------
// x: f32 -> bf16 elementwise, 8 elems/thread
// ---------------------------------------------------------------------------
__global__ __launch_bounds__(256)
void xconv_kernel(const float* __restrict__ x, bf16_t* __restrict__ xb)
{
    const size_t i = ((size_t)blockIdx.x * 256 + threadIdx.x) * 8;
    float4 a = *(const float4*)(x + i);
    float4 b = *(const float4*)(x + i + 4);
    bf16x8 o;
    o[0] = (bf16_t)a.x; o[1] = (bf16_t)a.y; o[2] = (bf16_t)a.z; o[3] = (bf16_t)a.w;
    o[4] = (bf16_t)b.x; o[5] = (bf16_t)b.y; o[6] = (bf16_t)b.z; o[7] = (bf16_t)b.w;
    *(bf16x8*)(xb + i) = o;
}

// ---------------------------------------------------------------------------
// W[K][N] f32 -> Wt[N][K] bf16 (64x64 LDS tile transpose; z picks weight)
// ---------------------------------------------------------------------------
__global__ __launch_bounds__(256)
void wtrans_kernel(const float* __restrict__ W0, const float* __restrict__ W1,
                   const float* __restrict__ W2, const float* __restrict__ W3,
                   bf16_t* __restrict__ T0, bf16_t* __restrict__ T1,
                   bf16_t* __restrict__ T2, bf16_t* __restrict__ T3)
{
    const float* W; bf16_t* T;
    switch (blockIdx.z) {
        case 0:  W = W0; T = T0; break;
        case 1:  W = W1; T = T1; break;
        case 2:  W = W2; T = T2; break;
        default: W = W3; T = T3; break;
    }
    __shared__ bf16_t tile[64 * 72];
    const int tid = threadIdx.x;
    const int r0 = blockIdx.y * 64;          // k block
    const int c0 = blockIdx.x * 64;          // n block

    const int rr = tid >> 4;
    const int cc = (tid & 15) * 4;
    #pragma unroll
    for (int i = 0; i < 4; ++i) {
        const int row = rr + i * 16;
        float4 v = *(const float4*)(W + (size_t)(r0 + row) * C_ + c0 + cc);
        tile[(cc + 0) * 72 + row] = (bf16_t)v.x;
        tile[(cc + 1) * 72 + row] = (bf16_t)v.y;
        tile[(cc + 2) * 72 + row] = (bf16_t)v.z;
        tile[(cc + 3) * 72 + row] = (bf16_t)v.w;
    }
    __syncthreads();
    #pragma unroll
    for (int i = 0; i < 2; ++i) {
        const int ch = i * 256 + tid;
        const int n  = ch >> 3;
        const int k8 = (ch & 7) * 8;
        bf16x8 o = *(const bf16x8*)&tile[n * 72 + k8];
        *(bf16x8*)(T + (size_t)(c0 + n) * C_ + r0 + k8) = o;
    }
}

// ---------------------------------------------------------------------------
// Fused QKV GEMM: A[8192,1024]bf16 @ Wqkv_t[3072,1024]^T + bias.
// 128x128 tile, BK=64 as TWO 32-wide LDS halves (row stride stays 64B ->
// conflict-free frag reads; naive BK=64 would be 128B stride = 16-way).
// Halves the barrier count vs BK=32 (16 iters).
// Epilogue routes by which = n0>>10: 0 -> Qb [B,H,N,D] PRE-SCALED by QSCALE,
// 1 -> Kb [B,H,N,D], 2 -> Vtb [B,H,D,N] (packed 8B stores).
// ---------------------------------------------------------------------------
__global__ __launch_bounds__(256)
void gemm_qkv_kernel(const bf16_t* __restrict__ A, const bf16_t* __restrict__ Wt,
                     const float* __restrict__ bq, const float* __restrict__ bk,
                     const float* __restrict__ bv,
                     bf16_t* __restrict__ Qb, bf16_t* __restrict__ Kb,
                     bf16_t* __restrict__ Vtb)
{
    __shared__ bf16_t As[2][128 * 32];
    __shared__ bf16_t Bs[2][128 * 32];

    const int tid  = threadIdx.x;
    const int w    = tid >> 6;
    const int lane = tid & 63;
    const int c    = lane & 15;
    const int quad = lane >> 4;
    const int n0   = blockIdx.x * 128;
    const int m0   = blockIdx.y * 128;
    const int wm   = (w & 1) * 64;
    const int wn   = (w >> 1) * 64;

    f32x4 acc[4][4] = {};

    for (int k0 = 0; k0 < C_; k0 += 64) {
        __syncthreads();
        #pragma unroll
        for (int hh = 0; hh < 2; ++hh) {
            #pragma unroll
            for (int ph = 0; ph < 2; ++ph) {
                const int ch  = ph * 256 + tid;
                const int row = ch >> 2;
                const int k8  = (ch & 3) * 8;
                const int wbase = (ph * 256 + w * 64) * 8;
                async16(A  + (size_t)(m0 + row) * C_ + k0 + hh * 32 + k8, &As[hh][wbase]);
                async16(Wt + (size_t)(n0 + row) * C_ + k0 + hh * 32 + k8, &Bs[hh][wbase]);
            }
        }
        __syncthreads();

        bf16x8 af[2][4], bfr[2][4];
        #pragma unroll
        for (int hh = 0; hh < 2; ++hh) {
            #pragma unroll
            for (int mf = 0; mf < 4; ++mf)
                af[hh][mf] = *(const bf16x8*)&As[hh][(wm + mf * 16 + c) * 32 + quad * 8];
            #pragma unroll
            for (int nf = 0; nf < 4; ++nf)
                bfr[hh][nf] = *(const bf16x8*)&Bs[hh][(wn + nf * 16 + c) * 32 + quad * 8];
        }

        #pragma unroll
        for (int mf = 0; mf < 4; ++mf)
            #pragma unroll
            for (int nf = 0; nf < 4; ++nf) {
                acc[mf][nf] = MFMA32(af[0][mf], bfr[0][nf], acc[mf][nf]);
                acc[mf][nf] = MFMA32(af[1][mf], bfr[1][nf], acc[mf][nf]);
            }
    }

    const int which = n0 >> 10;                 // 0 Q, 1 K, 2 V (tile-uniform)
    const float* bias = (which == 0) ? bq : (which == 1) ? bk : bv;

    #pragma unroll
    for (int nf = 0; nf < 4; ++nf) {
        const int col  = n0 + wn + nf * 16 + c;
        const int ncol = col & 1023;
        const float bsf = bias[ncol];
        const int h = ncol >> 6, d = ncol & 63;
        #pragma unroll
        for (int mf = 0; mf < 4; ++mf) {
            const int rbase = m0 + wm + mf * 16 + quad * 4;
            if (which < 2) {
                bf16_t* out = which ? Kb : Qb;
                const float sc = which ? 1.0f : QSCALE;
                #pragma unroll
                for (int r = 0; r < 4; ++r) {
                    const int row = rbase + r;
                    const int bb = row >> 11, n = row & 2047;
                    out[(((size_t)bb * H_ + h) * N_ + n) * D_ + d] =
                        (bf16_t)((acc[mf][nf][r] + bsf) * sc);
                }
            } else {
                const int bb = rbase >> 11, nb = rbase & 2047;
                bf16x4 o;
                #pragma unroll
                for (int r = 0; r < 4; ++r) o[r] = (bf16_t)(acc[mf][nf][r] + bsf);
                *(bf16x4*)(Vtb + (((size_t)bb * H_ + h) * D_ + d) * N_ + nb) = o;
            }
        }
    }
}

// ---------------------------------------------------------------------------
// Output GEMM: ctx[8192,1024]bf16 @ Wo_t[1024,1024]^T + bo -> f32 [8192,1024]
// Same BK=64 split-LDS structure.
// ---------------------------------------------------------------------------
__global__ __launch_bounds__(256)
void gemm_out_kernel(const bf16_t* __restrict__ A, const bf16_t* __restrict__ Bt,
                     const float* __restrict__ bias, float* __restrict__ out)
{
    __shared__ bf16_t As[2][128 * 32];
    __shared__ bf16_t Bs[2][128 * 32];

    const int tid  = threadIdx.x;
    const int w    = tid >> 6;
    const int lane = tid & 63;
    const int c    = lane & 15;
    const int quad = lane >> 4;
    const int n0   = blockIdx.x * 128;
    const int m0   = blockIdx.y * 128;
    const int wm   = (w & 1) * 64;
    const int wn   = (w >> 1) * 64;

    f32x4 acc[4][4] = {};

    for (int k0 = 0; k0 < C_; k0 += 64) {
        __syncthreads();
        #pragma unroll
        for (int hh = 0; hh < 2; ++hh) {
            #pragma unroll
            for (int ph = 0; ph < 2; ++ph) {
                const int ch  = ph * 256 + tid;
                const int row = ch >> 2;
                const int k8  = (ch & 3) * 8;
                const int wbase = (ph * 256 + w * 64) * 8;
                async16(A  + (size_t)(m0 + row) * C_ + k0 + hh * 32 + k8, &As[hh][wbase]);
                async16(Bt + (size_t)(n0 + row) * C_ + k0 + hh * 32 + k8, &Bs[hh][wbase]);
            }
        }
        __syncthreads();

        bf16x8 af[2][4], bfr[2][4];
        #pragma unroll
        for (int hh = 0; hh < 2; ++hh) {
            #pragma unroll
            for (int mf = 0; mf < 4; ++mf)
                af[hh][mf] = *(const bf16x8*)&As[hh][(wm + mf * 16 + c) * 32 + quad * 8];
            #pragma unroll
            for (int nf = 0; nf < 4; ++nf)
                bfr[hh][nf] = *(const bf16x8*)&Bs[hh][(wn + nf * 16 + c) * 32 + quad * 8];
        }

        #pragma unroll
        for (int mf = 0; mf < 4; ++mf)
            #pragma unroll
            for (int nf = 0; nf < 4; ++nf) {
                acc[mf][nf] = MFMA32(af[0][mf], bfr[0][nf], acc[mf][nf]);
                acc[mf][nf] = MFMA32(af[1][mf], bfr[1][nf], acc[mf][nf]);
            }
    }

    #pragma unroll
    for (int nf = 0; nf < 4; ++nf) {
        const int col   = n0 + wn + nf * 16 + c;
        const float bsf = bias[col];
        #pragma unroll
        for (int mf = 0; mf < 4; ++mf) {
            const int rbase = m0 + wm + mf * 16 + quad * 4;
            #pragma unroll
            for (int r = 0; r < 4; ++r)
                out[(size_t)(rbase + r) * C_ + col] = acc[mf][nf][r] + bsf;
        }
    }
}

// ---------------------------------------------------------------------------
// Attention, S^T formulation, no-rescale streaming softmax, prescaled Q.
// Block = 4 waves, 256 q (wave: 64 q = 4 groups of 16 sharing K/V frags).
// Key tiles of 64 staged in LDS (XOR-swizzled 16B chunks).
// launch_bounds(256,2): VGPR est ~185 incl. AGPR accs -- must NOT spill
// (round-6: spills cost ~47MB scratch traffic; watch WRITE_SIZE).
// Grid 512; bh = (bid&7)*8 + ((bid>>3)&7), qtile = bid>>6 (XCD L2 reuse).
// ---------------------------------------------------------------------------
__global__ __launch_bounds__(256, 2)
void attn_kernel(const bf16_t* __restrict__ Q, const bf16_t* __restrict__ K,
                 const bf16_t* __restrict__ Vt, bf16_t* __restrict__ ctx)
{
    __shared__ bf16_t ksh[64 * 64];
    __shared__ bf16_t vsh[64 * 64];

    const int tid  = threadIdx.x;
    const int w    = tid >> 6;
    const int lane = tid & 63;
    const int c    = lane & 15;
    const int quad = lane >> 4;

    const int bid   = blockIdx.x;
    const int bh    = (bid & 7) * 8 + ((bid >> 3) & 7);   // 0..63
    const int qtile = bid >> 6;                           // 0..7
    const int b = bh >> 4, h = bh & 15;
    const size_t base = (size_t)bh * N_ * D_;
    const int qb = qtile * 256 + w * 64;                  // wave's 64 q-rows

    bf16x8 qf[4][2];
    #pragma unroll
    for (int g = 0; g < 4; ++g)
        #pragma unroll
        for (int hh = 0; hh < 2; ++hh)
            qf[g][hh] = *(const bf16x8*)(Q + base + (size_t)(qb + g * 16 + c) * D_ + hh * 32 + quad * 8);

    bf16x8 ones;
    #pragma unroll
    for (int j = 0; j < 8; ++j) ones[j] = (bf16_t)1.0f;

    f32x4 O[4][4] = {};
    f32x4 O5[4] = {};                               // row-sum accumulators

    for (int kt = 0; kt < N_; kt += 64) {
        __syncthreads();
        #pragma unroll
        for (int ph = 0; ph < 2; ++ph) {
            const int ch = ph * 256 + tid;       // 0..511
            const int rr = ch >> 3;              // key (K) / d (V)
            const int e8 = ch & 7;
            const int sw = (e8 ^ (rr & 7)) * 8;
            bf16x8 kv = *(const bf16x8*)(K  + base + (size_t)(kt + rr) * D_ + e8 * 8);
            *(bf16x8*)&ksh[rr * 64 + sw] = kv;
            bf16x8 vv = *(const bf16x8*)(Vt + base + (size_t)rr * N_ + kt + e8 * 8);
            *(bf16x8*)&vsh[rr * 64 + sw] = vv;
        }
        __syncthreads();

        #pragma unroll
        for (int ss = 0; ss < 2; ++ss) {         // two 32-key sub-steps
            bf16x8 kb[2][2];
            #pragma unroll
            for (int s2 = 0; s2 < 2; ++s2) {
                const int key = (ss * 2 + s2) * 16 + c;
                #pragma unroll
                for (int hh = 0; hh < 2; ++hh)
                    kb[s2][hh] = *(const bf16x8*)&ksh[key * 64 + (((hh * 4 + quad) ^ (c & 7)) * 8)];
            }
            bf16x8 va[4];
            const int k8lo = ss * 4 + (quad >> 1);
            const int half = (quad & 1) * 4;
            #pragma unroll
            for (int df = 0; df < 4; ++df) {
                const int row = (df * 16 + c) * 64;
                bf16x4 lo = *(const bf16x4*)&vsh[row + ((k8lo       ^ (c & 7)) * 8) + half];
                bf16x4 hi = *(const bf16x4*)&vsh[row + (((k8lo + 2) ^ (c & 7)) * 8) + half];
                #pragma unroll
                for (int j = 0; j < 4; ++j) { va[df][j] = lo[j]; va[df][4 + j] = hi[j]; }
            }

            #pragma unroll
            for (int g = 0; g < 4; ++g) {
                f32x4 s0 = {}, s1 = {};
                s0 = MFMA32(kb[0][0], qf[g][0], s0);
                s0 = MFMA32(kb[0][1], qf[g][1], s0);
                s1 = MFMA32(kb[1][0], qf[g][0], s1);
                s1 = MFMA32(kb[1][1], qf[g][1], s1);

                bf16x8 pb;
                #pragma unroll
                for (int r = 0; r < 4; ++r) {
                    pb[r]     = (bf16_t)EXP2F(s0[r]);
                    pb[4 + r] = (bf16_t)EXP2F(s1[r]);
                }

                #pragma unroll
                for (int df = 0; df < 4; ++df)
                    O[g][df] = MFMA32(va[df], pb, O[g][df]);
                O5[g] = MFMA32(ones, pb, O5[g]);   // l accumulation
            }
        }
    }

    #pragma unroll
    for (int g = 0; g < 4; ++g) {
        const float inv_l = 1.0f / O5[g][0];       // full row-sum for q
        const int q = qb + g * 16 + c;
        #pragma unroll
        for (int df = 0; df < 4; ++df) {
            bf16x4 o;
            #pragma unroll
            for (int r = 0; r < 4; ++r) o[r] = (bf16_t)(O[g][df][r] * inv_l);
            *(bf16x4*)(ctx + ((size_t)b * N_ + q) * C_ + h * 64 + df * 16 + quad * 4) = o;
        }
    }
}

extern "C" void kernel_launch(void* const* d_in, const int* in_sizes, int n_in,
                              void* d_out, int out_size, void* d_ws, size_t ws_size,
                              hipStream_t stream) {
    const float* x  = (const float*)d_in[0];
    const float* Wq = (const float*)d_in[1];
    const float* bq = (const float*)d_in[2];
    const float* Wk = (const float*)d_in[3];
    const float* bk = (const float*)d_in[4];
    const float* Wv = (const float*)d_in[5];
    const float* bv = (const float*)d_in[6];
    const float* Wo = (const float*)d_in[7];
    const float* bo = (const float*)d_in[8];

    bf16_t* ws = (bf16_t*)d_ws;
    const size_t per = (size_t)B_ * N_ * C_;     // 8,388,608 elems
    bf16_t* xb  = ws;                            // reused as ctx after QKV
    bf16_t* ctx = ws;
    bf16_t* Qb  = ws + per;
    bf16_t* Kb  = ws + 2 * per;
    bf16_t* Vtb = ws + 3 * per;
    bf16_t* Wtqkv = ws + 4 * per;                // [3072][1024] concatenated
    bf16_t* Wtq = Wtqkv;
    bf16_t* Wtk = Wtqkv + (size_t)C_ * C_;
    bf16_t* Wtv = Wtqkv + 2 * (size_t)C_ * C_;
    bf16_t* Wto = Wtqkv + 3 * (size_t)C_ * C_;

    dim3 blk(256);

    xconv_kernel<<<dim3(per / 2048), blk, 0, stream>>>(x, xb);
    wtrans_kernel<<<dim3(16, 16, 4), blk, 0, stream>>>(Wq, Wk, Wv, Wo, Wtq, Wtk, Wtv, Wto);

    gemm_qkv_kernel<<<dim3(24, 64), blk, 0, stream>>>(xb, Wtqkv, bq, bk, bv, Qb, Kb, Vtb);

    attn_kernel<<<dim3(512), blk, 0, stream>>>(Qb, Kb, Vtb, ctx);

    gemm_out_kernel<<<dim3(8, 64), blk, 0, stream>>>(ctx, Wto, bo, (float*)d_out);
}